// Round 2
// baseline (700.037 us; speedup 1.0000x reference)
//
#include <hip/hip_runtime.h>

// DynamicMultiRNN: 2-layer shared-weight LSTM, B=1024 T=200 D=128, residual on L2.
// Persistent kernel: 64 blocks x 512 threads; block owns 16 batch rows for all 200
// steps (recurrence is batch-row-independent -> no inter-block sync needed).
// Weights [W;U] (256x512) live in per-wave VGPRs as bf16 (128 VGPRs/lane), loaded once.
// Wave w owns z col-tiles {w, w+8, w+16, w+24} == the i,f,g,o gate columns for
// h-cols [16w,16w+16): gates are computed fully in-register (no z via LDS).
//
// DTYPE-ADAPTIVE: a 1-thread pre-kernel probes x's bit patterns (f32 stream read
// as bf16 contains huge/NaN values; real bf16 N(0,1) doesn't) and writes a flag
// to d_ws; all global loads/stores branch (wave-uniformly) on it.

typedef __bf16 bf16_t;
typedef __bf16 bf16x8 __attribute__((ext_vector_type(8)));
typedef float f32x4 __attribute__((ext_vector_type(4)));

#define B_ 1024
#define T_ 200
#define D_ 128
#define G_ 512            // 4*D
#define AS 264            // A-tile row stride (elems): 256 + 8 pad, keeps 16B align

__device__ __forceinline__ float fast_sig(float v) {
    return __builtin_amdgcn_rcpf(1.0f + __builtin_amdgcn_exp2f(v * -1.44269504088896340736f));
}
__device__ __forceinline__ float fast_tanh(float v) {
    return 2.0f * __builtin_amdgcn_rcpf(1.0f + __builtin_amdgcn_exp2f(v * -2.88539008177792681472f)) - 1.0f;
}

__device__ __forceinline__ uint2 pack4_bf16(float a, float b, float c, float d) {
    union { bf16_t h[4]; uint2 u; } cv;
    cv.h[0] = (bf16_t)a; cv.h[1] = (bf16_t)b; cv.h[2] = (bf16_t)c; cv.h[3] = (bf16_t)d;
    return cv.u;
}

// Probe: interpret first 64 u16 of x as bf16. True-bf16 N(0,1) data -> max < 30.
// f32-stream-as-u16 -> low halves are ~uniform bf16 patterns, P(all < 1e4) ~ 5e-9.
__global__ void detect_dtype_kernel(const unsigned short* __restrict__ xw,
                                    int* __restrict__ flag) {
    float mx = 0.0f;
    for (int i = 0; i < 64; ++i) {
        unsigned int u = ((unsigned int)xw[i]) << 16;
        float v = __uint_as_float(u);
        v = fabsf(v);
        if (!(v <= 1e4f)) { mx = 1e30f; break; }   // catches huge / Inf / NaN
        if (v > mx) mx = v;
    }
    flag[0] = (mx > 1e4f) ? 1 : 0;                 // 1 = inputs are f32
}

__global__ __launch_bounds__(512, 2)
void lstm2_kernel(const void* __restrict__ xv,
                  const void* __restrict__ Wv,
                  const void* __restrict__ Uv,
                  const void* __restrict__ bv,
                  void* __restrict__ outv,
                  const int* __restrict__ flagp)
{
    const int is_f32 = flagp[0];   // wave-uniform

    // A1 = [x_t ; h1], A2 = [h1n ; h2], row-major [16 rows][256 k], bf16, padded
    __shared__ __align__(16) bf16_t A1[16 * AS];
    __shared__ __align__(16) bf16_t A2[16 * AS];

    const int tid  = threadIdx.x;
    const int w    = tid >> 6;          // wave 0..7
    const int lane = tid & 63;
    const int lo   = lane & 15;
    const int quad = lane >> 4;
    const int r0   = blockIdx.x * 16;   // batch-row base

    // zero-init activation tiles (h1 = h2 = 0 at t=0)
    for (int i = tid; i < 16 * AS; i += 512) {
        A1[i] = (bf16_t)0.0f;
        A2[i] = (bf16_t)0.0f;
    }

    // ---- load weight fragments into registers (once; reused 400x) ----
    // B-frag for mfma_f32_16x16x32_bf16: lane holds B[k][n], n=16*ct+(lane&15),
    // k=32*kt+(lane>>4)*8+j. Stacked K: k<128 -> W[k][:], else U[k-128][:].
    // Wave w's col-tiles: ct = w + 8*c  (c = gate: i,f,g,o)
    bf16x8 Breg[8][4];
    if (is_f32) {
        const float* Wf = (const float*)Wv;
        const float* Uf = (const float*)Uv;
        #pragma unroll
        for (int kt = 0; kt < 8; ++kt) {
            const int k0 = kt * 32 + quad * 8;
            #pragma unroll
            for (int c = 0; c < 4; ++c) {
                const int n = (w + 8 * c) * 16 + lo;
                const float* src = (k0 < 128) ? (Wf + (size_t)k0 * G_ + n)
                                              : (Uf + (size_t)(k0 - 128) * G_ + n);
                bf16x8 v;
                #pragma unroll
                for (int jj = 0; jj < 8; ++jj) v[jj] = (bf16_t)src[(size_t)jj * G_];
                Breg[kt][c] = v;
            }
        }
    } else {
        const bf16_t* Wb = (const bf16_t*)Wv;
        const bf16_t* Ub = (const bf16_t*)Uv;
        #pragma unroll
        for (int kt = 0; kt < 8; ++kt) {
            const int k0 = kt * 32 + quad * 8;
            #pragma unroll
            for (int c = 0; c < 4; ++c) {
                const int n = (w + 8 * c) * 16 + lo;
                const bf16_t* src = (k0 < 128) ? (Wb + (size_t)k0 * G_ + n)
                                               : (Ub + (size_t)(k0 - 128) * G_ + n);
                bf16x8 v;
                #pragma unroll
                for (int jj = 0; jj < 8; ++jj) v[jj] = src[(size_t)jj * G_];
                Breg[kt][c] = v;
            }
        }
    }

    // lane's gate column j and its 4 gate biases (i,f,g,o at j+128c)
    const int j = w * 16 + lo;
    float bj[4];
    if (is_f32) {
        const float* bf = (const float*)bv;
        #pragma unroll
        for (int c = 0; c < 4; ++c) bj[c] = bf[j + 128 * c];
    } else {
        const bf16_t* bb = (const bf16_t*)bv;
        #pragma unroll
        for (int c = 0; c < 4; ++c) bj[c] = (float)bb[j + 128 * c];
    }

    // x staging: each thread moves 4 elements; row = tid/32, col = (tid%32)*4
    const int xrow = tid >> 5;
    const int xcol = (tid & 31) * 4;
    const size_t xbase = (size_t)(r0 + xrow) * T_ * D_ + xcol;
    const float*  xf = (const float*)xv;
    const bf16_t* xb = (const bf16_t*)xv;

    __syncthreads();                    // zeros visible
    // stage x_0
    {
        uint2 s;
        if (is_f32) {
            float4 f = *reinterpret_cast<const float4*>(xf + xbase);
            s = pack4_bf16(f.x, f.y, f.z, f.w);
        } else {
            s = *reinterpret_cast<const uint2*>(xb + xbase);
        }
        *reinterpret_cast<uint2*>(&A1[xrow * AS + xcol]) = s;
    }

    float c1[4] = {0.f, 0.f, 0.f, 0.f};
    float c2[4] = {0.f, 0.f, 0.f, 0.f};
    float* fout = (float*)outv;
    bf16_t* bout = (bf16_t*)outv;
    __syncthreads();                    // A1/A2 ready for t=0

    for (int t = 0; t < T_; ++t) {
        // prefetch x_{t+1}
        uint2 xstage = make_uint2(0u, 0u);
        if (t + 1 < T_) {
            if (is_f32) {
                float4 f = *reinterpret_cast<const float4*>(xf + xbase + (size_t)(t + 1) * D_);
                xstage = pack4_bf16(f.x, f.y, f.z, f.w);
            } else {
                xstage = *reinterpret_cast<const uint2*>(xb + xbase + (size_t)(t + 1) * D_);
            }
        }

        // ---- layer 1: z1 = [x_t ; h1] @ [W;U] ----
        f32x4 acc[4];
        #pragma unroll
        for (int c = 0; c < 4; ++c) acc[c] = (f32x4){0.f, 0.f, 0.f, 0.f};
        #pragma unroll
        for (int kt = 0; kt < 8; ++kt) {
            bf16x8 af = *reinterpret_cast<const bf16x8*>(&A1[lo * AS + kt * 32 + quad * 8]);
            #pragma unroll
            for (int c = 0; c < 4; ++c)
                acc[c] = __builtin_amdgcn_mfma_f32_16x16x32_bf16(af, Breg[kt][c], acc[c], 0, 0, 0);
        }

        // gates layer 1 — acc[c][q] = z[row quad*4+q][j + 128*c], in-lane
        float h1n[4];
        #pragma unroll
        for (int q = 0; q < 4; ++q) {
            float ig = fast_sig (acc[0][q] + bj[0]);
            float fg = fast_sig (acc[1][q] + bj[1]);
            float gg = fast_tanh(acc[2][q] + bj[2]);
            float og = fast_sig (acc[3][q] + bj[3]);
            c1[q]  = fg * c1[q] + ig * gg;
            h1n[q] = og * fast_tanh(c1[q]);
        }

        __syncthreads();   // S1: all waves done reading A1 (and A2's h2 half)

        // h1n -> A2[:,0:128] (L2 input) and A1[:,128:256] (next-step h1);
        // x_{t+1} -> A1[:,0:128]
        #pragma unroll
        for (int q = 0; q < 4; ++q) {
            const int rq = quad * 4 + q;
            bf16_t hb = (bf16_t)h1n[q];
            A2[rq * AS + j] = hb;
            A1[rq * AS + 128 + j] = hb;
        }
        if (t + 1 < T_)
            *reinterpret_cast<uint2*>(&A1[xrow * AS + xcol]) = xstage;

        __syncthreads();   // S2: A2 = [h1n ; h2] complete

        // ---- layer 2: z2 = [h1n ; h2] @ [W;U]  (shared weights) ----
        #pragma unroll
        for (int c = 0; c < 4; ++c) acc[c] = (f32x4){0.f, 0.f, 0.f, 0.f};
        #pragma unroll
        for (int kt = 0; kt < 8; ++kt) {
            bf16x8 af = *reinterpret_cast<const bf16x8*>(&A2[lo * AS + kt * 32 + quad * 8]);
            #pragma unroll
            for (int c = 0; c < 4; ++c)
                acc[c] = __builtin_amdgcn_mfma_f32_16x16x32_bf16(af, Breg[kt][c], acc[c], 0, 0, 0);
        }

        // gates layer 2 + residual (h1n kept in f32 regs, matching ref)
        float h2n[4];
        #pragma unroll
        for (int q = 0; q < 4; ++q) {
            float ig = fast_sig (acc[0][q] + bj[0]);
            float fg = fast_sig (acc[1][q] + bj[1]);
            float gg = fast_tanh(acc[2][q] + bj[2]);
            float og = fast_sig (acc[3][q] + bj[3]);
            c2[q]  = fg * c2[q] + ig * gg;
            h2n[q] = og * fast_tanh(c2[q]) + h1n[q];
        }

        __syncthreads();   // S3: all waves done reading A2 before h2 overwrite

        if (is_f32) {
            #pragma unroll
            for (int q = 0; q < 4; ++q) {
                const int rq = quad * 4 + q;
                A2[rq * AS + 128 + j] = (bf16_t)h2n[q];
                fout[(size_t)(r0 + rq) * T_ * D_ + (size_t)t * D_ + j] = h2n[q];
            }
        } else {
            #pragma unroll
            for (int q = 0; q < 4; ++q) {
                const int rq = quad * 4 + q;
                bf16_t hb = (bf16_t)h2n[q];
                A2[rq * AS + 128 + j] = hb;
                bout[(size_t)(r0 + rq) * T_ * D_ + (size_t)t * D_ + j] = hb;
            }
        }
    }
}

extern "C" void kernel_launch(void* const* d_in, const int* in_sizes, int n_in,
                              void* d_out, int out_size, void* d_ws, size_t ws_size,
                              hipStream_t stream) {
    const void* x  = d_in[0];
    const void* W  = d_in[1];
    const void* U  = d_in[2];
    const void* b  = d_in[3];
    // d_in[4] = seq_len (int32) — intentionally ignored, matching the reference.
    int* flag = (int*)d_ws;

    detect_dtype_kernel<<<dim3(1), dim3(1), 0, stream>>>((const unsigned short*)x, flag);
    lstm2_kernel<<<dim3(B_ / 16), dim3(512), 0, stream>>>(x, W, U, b, d_out, flag);
}

// Round 3
// 655.960 us; speedup vs baseline: 1.0672x; 1.0672x over previous
//
#include <hip/hip_runtime.h>

// DynamicMultiRNN: 2-layer shared-weight LSTM, B=1024 T=200 D=128, residual on L2.
// Inputs/outputs are f32 (confirmed R2: WRITE_SIZE == B*T*D*4B); MFMA in bf16.
//
// Persistent kernel: 64 blocks x 512 threads; block owns 16 batch rows for all
// steps (batch-row-independent recurrence -> no inter-block sync).
// Weights [W;U] (256x512) in per-wave registers as bf16 (32 x bf16x8 per lane).
// Wave w owns z col-tiles {w, w+8, w+16, w+24} == i,f,g,o gate columns for
// h-cols [16w,16w+16): gates fully in-register.
//
// ONE barrier per step: LDS activations double-buffered (A[2] x {x,h1,h2}
// panels); iteration i computes layer1@i AND layer2@(i-1) (1-step software
// pipeline), reading buffer i&1, writing buffer (i+1)&1. The top-of-loop
// barrier orders iter i-1 reads before iter i writes (WAR) and iter i-1
// h1n/h2n/x writes before iter i reads (RAW). h1 panel fragments are shared
// between L1's U-half and L2's W-half: 12 (not 16) ds_read_b128/lane/step.

typedef __bf16 bf16_t;
typedef __bf16 bf16x8 __attribute__((ext_vector_type(8)));
typedef float f32x4 __attribute__((ext_vector_type(4)));

#define B_ 1024
#define T_ 200
#define D_ 128
#define G_ 512            // 4*D
#define RS 136            // panel row stride, bf16 elems (272 B, 16B-aligned)
#define PANEL (16 * RS)

__device__ __forceinline__ float fast_sig(float v) {
    return __builtin_amdgcn_rcpf(1.0f + __builtin_amdgcn_exp2f(v * -1.44269504088896340736f));
}
__device__ __forceinline__ float fast_tanh(float v) {
    return 2.0f * __builtin_amdgcn_rcpf(1.0f + __builtin_amdgcn_exp2f(v * -2.88539008177792681472f)) - 1.0f;
}
__device__ __forceinline__ uint2 pack4_bf16(float4 f) {
    union { bf16_t h[4]; uint2 u; } cv;
    cv.h[0] = (bf16_t)f.x; cv.h[1] = (bf16_t)f.y;
    cv.h[2] = (bf16_t)f.z; cv.h[3] = (bf16_t)f.w;
    return cv.u;
}

__global__ __launch_bounds__(512, 2)
void lstm2_kernel(const float* __restrict__ x,
                  const float* __restrict__ W,
                  const float* __restrict__ U,
                  const float* __restrict__ bias,
                  float* __restrict__ out)
{
    // A[buf][panel][16 rows x RS]; panel 0 = x_t, 1 = h1, 2 = h2
    __shared__ __align__(16) bf16_t A[2][3][PANEL];

    const int tid  = threadIdx.x;
    const int w    = tid >> 6;          // wave 0..7
    const int lane = tid & 63;
    const int lo   = lane & 15;
    const int quad = lane >> 4;
    const int r0   = blockIdx.x * 16;   // batch-row base

    // zero all LDS (h1(-1)=h2(-1)=0; unused-garbage panels must be finite)
    {
        unsigned int* a32 = (unsigned int*)&A[0][0][0];
        for (int i = tid; i < 2 * 3 * PANEL / 2; i += 512) a32[i] = 0u;
    }

    // ---- weight fragments (f32 global -> bf16 regs), reused 400x ----
    // B-frag mfma_f32_16x16x32_bf16: lane holds B[k][n], n=16*ct+lo,
    // k=32*kt+quad*8+jj. k<128 -> W, else U. Wave w's ct = w + 8*c.
    bf16x8 Breg[8][4];
    #pragma unroll
    for (int kt = 0; kt < 8; ++kt) {
        const int k0 = kt * 32 + quad * 8;
        #pragma unroll
        for (int c = 0; c < 4; ++c) {
            const int n = (w + 8 * c) * 16 + lo;
            const float* src = (k0 < 128) ? (W + (size_t)k0 * G_ + n)
                                          : (U + (size_t)(k0 - 128) * G_ + n);
            bf16x8 v;
            #pragma unroll
            for (int jj = 0; jj < 8; ++jj) v[jj] = (bf16_t)src[(size_t)jj * G_];
            Breg[kt][c] = v;
        }
    }

    // lane's gate column j; biases for i,f,g,o at j + 128*c
    const int j = w * 16 + lo;
    float bj[4];
    #pragma unroll
    for (int c = 0; c < 4; ++c) bj[c] = bias[j + 128 * c];

    // x staging: thread moves 4 f32 -> 4 bf16; row = tid/32, col = (tid%32)*4
    const int xrow = tid >> 5;
    const int xcol = (tid & 31) * 4;
    const size_t xbase = (size_t)(r0 + xrow) * T_ * D_ + xcol;

    // stage x(0) into buffer 0 (no barrier needed vs zeroing: same thread's
    // region, and the loop-top barrier publishes everything before iter 0 reads)
    *reinterpret_cast<uint2*>(&A[0][0][xrow * RS + xcol]) =
        pack4_bf16(*reinterpret_cast<const float4*>(x + xbase));

    float c1[4] = {0.f, 0.f, 0.f, 0.f};
    float c2[4] = {0.f, 0.f, 0.f, 0.f};
    float h1prev[4] = {0.f, 0.f, 0.f, 0.f};   // h1n(i-1), lane's own (rq, j)

    const int fo = lo * RS + quad * 8;        // fragment base offset in a panel

    // iteration i: layer1@i (i<T) + layer2@(i-1) (i>=1); 201 iterations
    for (int i = 0; i <= T_; ++i) {
        __syncthreads();                      // the ONE barrier
        const int pb = i & 1;

        // global prefetch x(i+1)
        uint2 xstage;
        const bool do_x = (i + 1 < T_);
        if (do_x)
            xstage = pack4_bf16(*reinterpret_cast<const float4*>(
                x + xbase + (size_t)(i + 1) * D_));

        // ---- 12 fragment loads (h1 frags shared by both layers) ----
        bf16x8 xf[4], h1f[4], h2f[4];
        #pragma unroll
        for (int kt = 0; kt < 4; ++kt) {
            xf[kt]  = *reinterpret_cast<const bf16x8*>(&A[pb][0][fo + kt * 32]);
            h1f[kt] = *reinterpret_cast<const bf16x8*>(&A[pb][1][fo + kt * 32]);
            h2f[kt] = *reinterpret_cast<const bf16x8*>(&A[pb][2][fo + kt * 32]);
        }

        // ---- two independent GEMMs: z1(i) = [x(i);h1(i-1)]@[W;U],
        //                             z2(i-1) = [h1n(i-1);h2(i-2)]@[W;U] ----
        f32x4 acc1[4], acc2[4];
        #pragma unroll
        for (int c = 0; c < 4; ++c) {
            acc1[c] = (f32x4){0.f, 0.f, 0.f, 0.f};
            acc2[c] = (f32x4){0.f, 0.f, 0.f, 0.f};
        }
        #pragma unroll
        for (int kt = 0; kt < 4; ++kt) {
            #pragma unroll
            for (int c = 0; c < 4; ++c) {
                acc1[c] = __builtin_amdgcn_mfma_f32_16x16x32_bf16(xf[kt],  Breg[kt][c],     acc1[c], 0, 0, 0);
                acc2[c] = __builtin_amdgcn_mfma_f32_16x16x32_bf16(h1f[kt], Breg[kt][c],     acc2[c], 0, 0, 0);
            }
        }
        #pragma unroll
        for (int kt = 0; kt < 4; ++kt) {
            #pragma unroll
            for (int c = 0; c < 4; ++c) {
                acc1[c] = __builtin_amdgcn_mfma_f32_16x16x32_bf16(h1f[kt], Breg[kt + 4][c], acc1[c], 0, 0, 0);
                acc2[c] = __builtin_amdgcn_mfma_f32_16x16x32_bf16(h2f[kt], Breg[kt + 4][c], acc2[c], 0, 0, 0);
            }
        }

        // ---- gates layer 1 @ step i (acc1[c][q] = z1[rq][j+128c]) ----
        float h1new[4];
        if (i < T_) {
            #pragma unroll
            for (int q = 0; q < 4; ++q) {
                float ig = fast_sig (acc1[0][q] + bj[0]);
                float fg = fast_sig (acc1[1][q] + bj[1]);
                float gg = fast_tanh(acc1[2][q] + bj[2]);
                float og = fast_sig (acc1[3][q] + bj[3]);
                c1[q]  = fg * c1[q] + ig * gg;
                h1new[q] = og * fast_tanh(c1[q]);
                A[pb ^ 1][1][(quad * 4 + q) * RS + j] = (bf16_t)h1new[q];
            }
            if (do_x)
                *reinterpret_cast<uint2*>(&A[pb ^ 1][0][xrow * RS + xcol]) = xstage;
        }

        // ---- gates layer 2 @ step i-1 (+ residual h1prev), output store ----
        if (i >= 1) {
            #pragma unroll
            for (int q = 0; q < 4; ++q) {
                float ig = fast_sig (acc2[0][q] + bj[0]);
                float fg = fast_sig (acc2[1][q] + bj[1]);
                float gg = fast_tanh(acc2[2][q] + bj[2]);
                float og = fast_sig (acc2[3][q] + bj[3]);
                c2[q]  = fg * c2[q] + ig * gg;
                float h2n = og * fast_tanh(c2[q]) + h1prev[q];
                const int rq = quad * 4 + q;
                A[pb ^ 1][2][rq * RS + j] = (bf16_t)h2n;
                out[(size_t)(r0 + rq) * T_ * D_ + (size_t)(i - 1) * D_ + j] = h2n;
            }
        }

        if (i < T_) {
            #pragma unroll
            for (int q = 0; q < 4; ++q) h1prev[q] = h1new[q];
        }
    }
}

extern "C" void kernel_launch(void* const* d_in, const int* in_sizes, int n_in,
                              void* d_out, int out_size, void* d_ws, size_t ws_size,
                              hipStream_t stream) {
    const float* x = (const float*)d_in[0];
    const float* W = (const float*)d_in[1];
    const float* U = (const float*)d_in[2];
    const float* b = (const float*)d_in[3];
    // d_in[4] = seq_len (int32) — intentionally ignored, matching the reference.
    float* out = (float*)d_out;

    lstm2_kernel<<<dim3(B_ / 16), dim3(512), 0, stream>>>(x, W, U, b, out);
}

// Round 5
// 406.658 us; speedup vs baseline: 1.7214x; 1.6131x over previous
//
#include <hip/hip_runtime.h>

// DynamicMultiRNN: 2-layer shared-weight LSTM, B=1024 T=200 D=128, residual on L2.
// f32 I/O (confirmed R2), bf16 MFMA internals.
//
// R5 = R4 with the LDS row-stride bug fixed (RS 136 -> 264; R4's packed rows
// are 256 columns wide and were overflowing into neighboring rows/buffers).
//
// PACKED A-TILE: both layers share [W;U], so one 16x256 A-tile holds
// rows 0-7  = [x(i)     | h1(i-1)]  (layer-1 inputs, 8 batch rows)
// rows 8-15 = [h1n(i-1) | h2(i-2)]  (layer-2 inputs, same 8 batch rows)
// One GEMM -> z1 and z2 together: 32 MFMAs/wave/iter, 8 ds_read_b128/lane,
// 4 gate cells/lane. 128 blocks x 512 thr -> 128 CUs.
// Lanes 0-31 do L1 gates (carry c1), lanes 32-63 do L2 gates (carry c2),
// branchless; f32 h1n residual crosses halves via __shfl_xor(.,32).
// Double-buffered LDS + single barrier/iter; 1-step software pipeline
// (iter i computes L1@i and L2@(i-1)); 201 iterations.

typedef __bf16 bf16_t;
typedef __bf16 bf16x8 __attribute__((ext_vector_type(8)));
typedef float f32x4 __attribute__((ext_vector_type(4)));

#define B_ 1024
#define T_ 200
#define D_ 128
#define G_ 512            // 4*D
#define RS 264            // A-tile row stride, bf16 elems: 256 cols + 8 pad (528 B)

__device__ __forceinline__ float fast_sig(float v) {
    return __builtin_amdgcn_rcpf(1.0f + __builtin_amdgcn_exp2f(v * -1.44269504088896340736f));
}
__device__ __forceinline__ float fast_tanh(float v) {
    return 2.0f * __builtin_amdgcn_rcpf(1.0f + __builtin_amdgcn_exp2f(v * -2.88539008177792681472f)) - 1.0f;
}
__device__ __forceinline__ unsigned int pack2_bf16(float2 f) {
    union { bf16_t h[2]; unsigned int u; } cv;
    cv.h[0] = (bf16_t)f.x; cv.h[1] = (bf16_t)f.y;
    return cv.u;
}

__global__ __launch_bounds__(512, 2)
void lstm2_kernel(const float* __restrict__ x,
                  const float* __restrict__ W,
                  const float* __restrict__ U,
                  const float* __restrict__ bias,
                  float* __restrict__ out)
{
    __shared__ __align__(16) bf16_t A[2][16 * RS];   // double-buffered packed tile

    const int tid  = threadIdx.x;
    const int w    = tid >> 6;           // wave 0..7
    const int lane = tid & 63;
    const int lo   = lane & 15;
    const int quad = lane >> 4;
    const bool isL2 = (lane >= 32);      // quads 2,3 -> A-rows 8..15 (layer 2)
    const int r0   = blockIdx.x * 8;     // 8 batch rows per block

    // zero both buffers (h1(-1)=h2(-2)=h2(-1)=0; everything finite)
    {
        unsigned int* a32 = (unsigned int*)&A[0][0];
        for (int i = tid; i < 2 * 16 * RS / 2; i += 512) a32[i] = 0u;
    }

    // ---- weight fragments (f32 -> bf16 regs), loaded once, reused 201x ----
    // B-frag mfma_f32_16x16x32_bf16: lane holds B[k][n], n = 16*ct + lo,
    // k = 32*kt + quad*8 + jj. k<128 -> W row k, else U row k-128.
    // Wave w's col-tiles ct = w + 8*c (c = gate i,f,g,o).
    bf16x8 Breg[8][4];
    #pragma unroll
    for (int kt = 0; kt < 8; ++kt) {
        const int k0 = kt * 32 + quad * 8;
        #pragma unroll
        for (int c = 0; c < 4; ++c) {
            const int n = (w + 8 * c) * 16 + lo;
            const float* src = (k0 < 128) ? (W + (size_t)k0 * G_ + n)
                                          : (U + (size_t)(k0 - 128) * G_ + n);
            bf16x8 v;
            #pragma unroll
            for (int jj = 0; jj < 8; ++jj) v[jj] = (bf16_t)src[(size_t)jj * G_];
            Breg[kt][c] = v;
        }
    }

    // lane's gate column j; biases i,f,g,o at j + 128*c
    const int j = w * 16 + lo;
    float bj[4];
    #pragma unroll
    for (int c = 0; c < 4; ++c) bj[c] = bias[j + 128 * c];

    // x staging: 512 threads x float2 -> 2 bf16; row = tid/64 (0..7), col = (tid%64)*2
    const int xrow = tid >> 6;
    const int xcol = (tid & 63) * 2;
    const size_t xbase = (size_t)(r0 + xrow) * T_ * D_ + xcol;

    // stage x(0) into buffer 0, rows 0-7 cols 0-127
    *reinterpret_cast<unsigned int*>(&A[0][xrow * RS + xcol]) =
        pack2_bf16(*reinterpret_cast<const float2*>(x + xbase));

    float cst[4]    = {0.f, 0.f, 0.f, 0.f};   // c1 (lanes<32) or c2 (lanes>=32)
    float h1prev[4] = {0.f, 0.f, 0.f, 0.f};   // L2 lanes: h1n(i-1) f32, via shfl

    const int fo = lo * RS + quad * 8;        // A-fragment base offset

    for (int i = 0; i <= T_; ++i) {
        __syncthreads();                      // the one barrier
        const int pb = i & 1;
        const int nb = pb ^ 1;

        // global prefetch x(i+1)
        float2 xv;
        const bool do_x = (i + 1 < T_);
        if (do_x)
            xv = *reinterpret_cast<const float2*>(x + xbase + (size_t)(i + 1) * D_);

        // ---- 8 fragment loads + one packed GEMM (z1 rows 0-7, z2 rows 8-15) ----
        f32x4 acc[4];
        #pragma unroll
        for (int c = 0; c < 4; ++c) acc[c] = (f32x4){0.f, 0.f, 0.f, 0.f};
        #pragma unroll
        for (int kt = 0; kt < 8; ++kt) {
            bf16x8 af = *reinterpret_cast<const bf16x8*>(&A[pb][fo + kt * 32]);
            #pragma unroll
            for (int c = 0; c < 4; ++c)
                acc[c] = __builtin_amdgcn_mfma_f32_16x16x32_bf16(af, Breg[kt][c], acc[c], 0, 0, 0);
        }

        // ---- gates, branchless across halves; acc[c][q] = z[quad*4+q][j+128c] ----
        // L1 lanes active for i<T (computing step i); L2 lanes for i>=1 (step i-1)
        const bool upd = isL2 ? (i >= 1) : (i < T_);
        float hnew[4];
        #pragma unroll
        for (int q = 0; q < 4; ++q) {
            float ig = fast_sig (acc[0][q] + bj[0]);
            float fg = fast_sig (acc[1][q] + bj[1]);
            float gg = fast_tanh(acc[2][q] + bj[2]);
            float og = fast_sig (acc[3][q] + bj[3]);
            float cn = fg * cst[q] + ig * gg;
            float hn = og * fast_tanh(cn) + (isL2 ? h1prev[q] : 0.0f);
            cst[q]  = upd ? cn : cst[q];
            hnew[q] = upd ? hn : 0.0f;        // 0 keeps LDS clean at edge steps
        }

        // ---- writes to next buffer ----
        // all lanes: own next-state h (L1 rows 0-7 / L2 rows 8-15, cols 128-255)
        #pragma unroll
        for (int q = 0; q < 4; ++q)
            A[nb][(quad * 4 + q) * RS + 128 + j] = (bf16_t)hnew[q];
        // L1 lanes: h1n(i) is also layer-2's next input (rows 8-15, cols 0-127)
        if (!isL2) {
            #pragma unroll
            for (int q = 0; q < 4; ++q)
                A[nb][(8 + quad * 4 + q) * RS + j] = (bf16_t)hnew[q];
        }
        // L2 lanes: emit y(i-1) = h2n (hnew already includes the residual)
        if (i >= 1 && isL2) {
            #pragma unroll
            for (int q = 0; q < 4; ++q) {
                const int rb = (quad - 2) * 4 + q;   // batch-row within block
                out[(size_t)(r0 + rb) * T_ * D_ + (size_t)(i - 1) * D_ + j] = hnew[q];
            }
        }
        // x(i+1) -> rows 0-7, cols 0-127
        if (do_x)
            *reinterpret_cast<unsigned int*>(&A[nb][xrow * RS + xcol]) = pack2_bf16(xv);

        // pass f32 h1n(i) from L1 half to L2 half (same wave, lane ^ 32)
        #pragma unroll
        for (int q = 0; q < 4; ++q)
            h1prev[q] = __shfl_xor(hnew[q], 32, 64);
    }
}

extern "C" void kernel_launch(void* const* d_in, const int* in_sizes, int n_in,
                              void* d_out, int out_size, void* d_ws, size_t ws_size,
                              hipStream_t stream) {
    const float* x = (const float*)d_in[0];
    const float* W = (const float*)d_in[1];
    const float* U = (const float*)d_in[2];
    const float* b = (const float*)d_in[3];
    // d_in[4] = seq_len (int32) — intentionally ignored, matching the reference.
    float* out = (float*)d_out;

    lstm2_kernel<<<dim3(B_ / 8), dim3(512), 0, stream>>>(x, W, U, b, out);
}